// Round 16
// baseline (302.019 us; speedup 1.0000x reference)
//
#include <hip/hip_runtime.h>

#define NPTS 4096
#define NBATCH 4
#define HDIM 192
#define CDIM 384
#define FINF 3.4e38f

typedef _Float16 f16x8 __attribute__((ext_vector_type(8)));
typedef float f32x4 __attribute__((ext_vector_type(4)));

// ---------------- K0: W2 [192][384] f32 -> fragment-major f16 chunks (R12, unchanged) --
__global__ __launch_bounds__(256) void prep_w2(const float* __restrict__ W2,
                                               _Float16* __restrict__ W2F) {
  const int j = blockIdx.x * 256 + threadIdx.x;   // 9216 chunks
  if (j < 9216) {
    const int lane = j & 63, r = lane & 15, kg = lane >> 4;
    const int kt = (j >> 6) % 6, ct = j / 384;
    const int c = ct * 16 + r, h0 = kt * 32 + kg * 8;
    f16x8 v;
#pragma unroll
    for (int e = 0; e < 8; ++e) v[e] = (_Float16)W2[(size_t)(h0 + e) * CDIM + c];
    *(f16x8*)(W2F + (size_t)j * 8) = v;
  }
}

// ---------------- KA: per-batch x-BUCKETING + suffix-min/prefix-max slab bounds --------
// Within-bin order nondeterministic (atomic arrival) — harmless: selection is exact lex
// top-16 over all points; skip bounds are SUFFIX-MIN/PREFIX-MAX over measured slab
// bounds, so exclusion covers ALL remaining slabs (overlap-safe where per-slab isn't).
__global__ __launch_bounds__(1024) void bucket_kernel(const float* __restrict__ pts,
                                                      float4* __restrict__ sp4,
                                                      float* __restrict__ bnds) {
  __shared__ float sx[4096];
  __shared__ float sxs[4096];
  __shared__ unsigned hist[64];
  __shared__ float rmn_s[16], rmx_s[16];
  __shared__ float smn[16], smx[16];
  __shared__ float gmin_s, ginvw_s;
  const int b = blockIdx.x;
  const float* P = pts + (size_t)b * NPTS * 3;
  const int t = threadIdx.x;

  float mn = FINF, mx = -FINF;
  for (int i = t; i < 4096; i += 1024) {
    const float x = P[3 * i];
    sx[i] = x;
    mn = fminf(mn, x);
    mx = fmaxf(mx, x);
  }
#pragma unroll
  for (int s = 32; s; s >>= 1) {
    mn = fminf(mn, __shfl_xor(mn, s));
    mx = fmaxf(mx, __shfl_xor(mx, s));
  }
  if ((t & 63) == 0) { rmn_s[t >> 6] = mn; rmx_s[t >> 6] = mx; }
  if (t < 64) hist[t] = 0;
  __syncthreads();
  if (t == 0) {
    float gmn = rmn_s[0], gmx = rmx_s[0];
    for (int i = 1; i < 16; ++i) { gmn = fminf(gmn, rmn_s[i]); gmx = fmaxf(gmx, rmx_s[i]); }
    gmin_s  = gmn;
    ginvw_s = (gmx > gmn) ? 64.0f / (gmx - gmn) : 0.0f;
  }
  __syncthreads();
  const float gmn = gmin_s, ginvw = ginvw_s;
  for (int i = t; i < 4096; i += 1024) {
    int bn = (int)((sx[i] - gmn) * ginvw);
    bn = bn < 0 ? 0 : (bn > 63 ? 63 : bn);
    atomicAdd(&hist[bn], 1u);
  }
  __syncthreads();
  if (t == 0) {
    unsigned run = 0;
    for (int i = 0; i < 64; ++i) { const unsigned c = hist[i]; hist[i] = run; run += c; }
  }
  __syncthreads();
  for (int i = t; i < 4096; i += 1024) {
    const float x = sx[i];
    int bn = (int)((x - gmn) * ginvw);
    bn = bn < 0 ? 0 : (bn > 63 ? 63 : bn);
    const unsigned pos = atomicAdd(&hist[bn], 1u);
    sp4[(size_t)b * 4096 + pos] =
        make_float4(x, P[3 * i + 1], P[3 * i + 2], __uint_as_float((unsigned)i));
    sxs[pos] = x;
  }
  __syncthreads();
  {  // per-256-slab measured x bounds (16 slabs, one wave each)
    const int rg = t >> 6, ln = t & 63;
    float rmn = FINF, rmx = -FINF;
    for (int k = ln; k < 256; k += 64) {
      const float v = sxs[rg * 256 + k];
      rmn = fminf(rmn, v);
      rmx = fmaxf(rmx, v);
    }
#pragma unroll
    for (int s = 32; s; s >>= 1) {
      rmn = fminf(rmn, __shfl_xor(rmn, s));
      rmx = fmaxf(rmx, __shfl_xor(rmx, s));
    }
    if (ln == 0) { smn[rg] = rmn; smx[rg] = rmx; }
  }
  __syncthreads();
  if (t == 0) {   // suffix-min of slab mins (hi side), prefix-max of slab maxes (lo side)
    float run = FINF;
    for (int s = 15; s >= 0; --s) { run = fminf(run, smn[s]); bnds[b * 64 + 32 + s] = run; }
    run = -FINF;
    for (int s = 0; s < 16; ++s)  { run = fmaxf(run, smx[s]); bnds[b * 64 + 48 + s] = run; }
  }
}

// ---------------- K1: KNN — block-cooperative outward slab scan ----------------
// 512 blocks x 512 thr; 32 bucketed-order queries/block; thread (ql, cid) takes 16 of
// each slab's 256 candidates -> every query's 16 threads share every slab (balanced;
// home slab bootstraps thresholds). Block-wide per-side exit via suffix/prefix bounds:
// gap^2 > te*1.0001+1e-6 => d > d16 strictly (exact exclusion). Forced PRUNE per slab
// keeps sThr current. Lex (d, orig j) everywhere (order-independent; R13/R15-verified).
#define SCAP 24   // per slab <=16 admits; trigger at 16; max cnt pre-check 23 < 24

#define PRUNE()                                                                      \
  do {                                                                               \
    int mc = cnt;                                                                    \
    _Pragma("unroll")                                                                \
    for (int s_ = 32; s_; s_ >>= 1) { int o_ = __shfl_xor(mc, s_); mc = mc > o_ ? mc : o_; } \
    mc = __builtin_amdgcn_readfirstlane(mc);                                         \
    for (int e = 0; e < mc; ++e) {                                                   \
      const int s = sstk[sbase + e] & 4095;                                          \
      const float dx = qx - spx[s];                                                  \
      const float dy = qy - spy[s];                                                  \
      const float dz = qz - spz[s];                                                  \
      const float d = __fadd_rn(__fadd_rn(__fmul_rn(dx, dx), __fmul_rn(dy, dy)),     \
                                __fmul_rn(dz, dz));                                  \
      const bool act = (e < cnt);                                                    \
      const float    dd = act ? d : FINF;                                            \
      const unsigned jj = act ? spw[s] : 0xFFFFFFFFu;                                \
      bool cc[16];                                                                   \
      _Pragma("unroll")                                                              \
      for (int i = 0; i < 16; ++i)                                                   \
        cc[i] = (dd < dl[i]) || (dd == dl[i] && jj < il[i]);                         \
      _Pragma("unroll")                                                              \
      for (int i = 15; i >= 1; --i) {                                                \
        dl[i] = cc[i] ? (cc[i - 1] ? dl[i - 1] : dd) : dl[i];                        \
        il[i] = cc[i] ? (cc[i - 1] ? il[i - 1] : jj) : il[i];                        \
      }                                                                              \
      dl[0] = cc[0] ? dd : dl[0];                                                    \
      il[0] = cc[0] ? jj : il[0];                                                    \
    }                                                                                \
    cnt = 0;                                                                         \
    thr = dl[15];                                                                    \
    atomicMin(&sThrU[ql], __float_as_uint(thr));                                     \
  } while (0)

#define PROC_SLAB(S)                                                                 \
  do {                                                                               \
    const int base_ = (S) * 256 + cid * 16;                                          \
    _Pragma("unroll")                                                                \
    for (int jt = 0; jt < 16; jt += 8) {                                             \
      const unsigned tb_ = ((volatile unsigned*)sThrU)[ql];                          \
      const float te = fminf(thr, __uint_as_float(tb_));                             \
      const int jb = base_ + jt;                                                     \
      const f32x4 x0 = *(const f32x4*)(spx + jb);                                    \
      const f32x4 x1 = *(const f32x4*)(spx + jb + 4);                                \
      const f32x4 y0 = *(const f32x4*)(spy + jb);                                    \
      const f32x4 y1 = *(const f32x4*)(spy + jb + 4);                                \
      const f32x4 z0 = *(const f32x4*)(spz + jb);                                    \
      const f32x4 z1 = *(const f32x4*)(spz + jb + 4);                                \
      _Pragma("unroll")                                                              \
      for (int u = 0; u < 8; ++u) {                                                  \
        const float px = (u < 4) ? x0[u & 3] : x1[u & 3];                            \
        const float py = (u < 4) ? y0[u & 3] : y1[u & 3];                            \
        const float pz = (u < 4) ? z0[u & 3] : z1[u & 3];                            \
        const float dx = qx - px;                                                    \
        const float dy = qy - py;                                                    \
        const float dz = qz - pz;                                                    \
        /* EXACT reference arithmetic: ((dx*dx+dy*dy)+dz*dz), f32, no FMA */         \
        const float d = __fadd_rn(__fadd_rn(__fmul_rn(dx, dx), __fmul_rn(dy, dy)),   \
                                  __fmul_rn(dz, dz));                                \
        if (d <= te) { sstk[sbase + cnt] = (unsigned short)(jb + u); ++cnt; }        \
      }                                                                              \
      if (__any(cnt >= SCAP - 8)) PRUNE();                                           \
    }                                                                                \
    PRUNE();   /* forced: sThr current at slab end */                                \
  } while (0)

__global__ __launch_bounds__(512) void knn_kernel(const float4* __restrict__ sp4,
                                                  const float* __restrict__ bnds,
                                                  int* __restrict__ idx_out) {
  __shared__ float smem[16384];             // 64KB: spx,spy,spz,spw; later md+mi alias
  __shared__ unsigned short sstk[12288];    // 24KB stacks; later od+oj alias
  __shared__ unsigned sThrU[32];
  __shared__ float sSuf[16], sPre[16];
  __shared__ int sFlag[2];

  float*    spx = smem;
  float*    spy = smem + 4096;
  float*    spz = smem + 8192;
  unsigned* spw = (unsigned*)(smem + 12288);

  const int t = threadIdx.x;
  const int b = blockIdx.x >> 7;            // 128 blocks per batch
  const int g = blockIdx.x & 127;           // query group (32 bucketed positions)
  const float4* SP = sp4 + (size_t)b * 4096;

  for (int i = t; i < 4096; i += 512) {
    const float4 v = SP[i];
    spx[i] = v.x; spy[i] = v.y; spz[i] = v.z;
    spw[i] = __float_as_uint(v.w);
  }
  if (t < 32) sThrU[t] = __float_as_uint(FINF);
  if (t < 16) { sSuf[t] = bnds[b * 64 + 32 + t]; sPre[t] = bnds[b * 64 + 48 + t]; }
  if (t < 2) sFlag[t] = 1;
  __syncthreads();

  const int ql  = t & 31;
  const int cid = (t >> 5) & 15;
  const int qpos = g * 32 + ql;
  const float qx = spx[qpos], qy = spy[qpos], qz = spz[qpos];
  const unsigned oq = spw[qpos];            // original row (captured pre-alias)

  float    dl[16];
  unsigned il[16];
#pragma unroll
  for (int i = 0; i < 16; ++i) { dl[i] = FINF; il[i] = 0xFFFFFFFFu; }
  float thr = FINF;
  int   cnt = 0;
  const int sbase = t * SCAP;

  const int sh = g >> 3;                    // home slab
  PROC_SLAB(sh);
  int  sHi = sh + 1, sLo = sh - 1;
  bool hiOpen = sHi < 16, loOpen = sLo >= 0;

  while (hiOpen || loOpen) {
    __syncthreads();                        // slab prunes' atomicMin visible
    if (t < 64) {                           // wave 0: block-wide exit tests
      const float teq = __uint_as_float(((volatile unsigned*)sThrU)[t & 31]);
      const float lim = teq * 1.0001f + 1e-6f;
      bool exH = true, exL = true;
      if (hiOpen) {
        const float gp = fmaxf(sSuf[sHi] - qx, 0.0f);   // min x of ALL remaining hi slabs
        exH = __fmul_rn(gp, gp) > lim;
      }
      if (loOpen) {
        const float gp = fmaxf(qx - sPre[sLo], 0.0f);   // max x of ALL remaining lo slabs
        exL = __fmul_rn(gp, gp) > lim;
      }
      const bool aH = __all(exH), aL = __all(exL);
      if ((t & 63) == 0) {
        if (aH) sFlag[0] = 0;
        if (aL) sFlag[1] = 0;
      }
    }
    __syncthreads();                        // flags visible (block-uniform from here)
    hiOpen = hiOpen && sFlag[0];
    loOpen = loOpen && sFlag[1];
    if (hiOpen) { PROC_SLAB(sHi); ++sHi; hiOpen = sHi < 16; }
    if (loOpen) { PROC_SLAB(sLo); --sLo; loOpen = sLo >= 0; }
  }

  __syncthreads();   // all scanning done -> alias merge arrays

  float*          md = smem;                               // f32[32*257]
  unsigned short* mi = (unsigned short*)(smem + 8224);     // u16[32*257]
  {
    const int lbase = ql * 257 + cid * 16;
#pragma unroll
    for (int i = 0; i < 16; ++i) {
      md[lbase + i] = dl[i];
      mi[lbase + i] = (unsigned short)il[i];
    }
  }
  __syncthreads();

  // stage 1: 16 lists -> 4 per query (128 thr), lex (d, orig j)
  float*          od = (float*)sstk;                           // f32[32*65]
  unsigned short* oj = (unsigned short*)((char*)sstk + 8320);  // u16[32*65]
  if (t < 128) {
    const int mq = t >> 2, grp = t & 3;
    const int base = mq * 257 + grp * 64;
    int p0 = 0, p1 = 0, p2 = 0, p3 = 0;
    const int ob = mq * 65 + grp * 16;
    for (int r = 0; r < 16; ++r) {
      const float d0 = md[base + p0];
      const float d1 = md[base + 16 + p1];
      const float d2 = md[base + 32 + p2];
      const float d3 = md[base + 48 + p3];
      const unsigned short j0 = mi[base + p0];
      const unsigned short j1 = mi[base + 16 + p1];
      const unsigned short j2 = mi[base + 32 + p2];
      const unsigned short j3 = mi[base + 48 + p3];
      float bd = d0; unsigned short bj = j0; int bw = 0;
      if (d1 < bd || (d1 == bd && j1 < bj)) { bd = d1; bj = j1; bw = 1; }
      if (d2 < bd || (d2 == bd && j2 < bj)) { bd = d2; bj = j2; bw = 2; }
      if (d3 < bd || (d3 == bd && j3 < bj)) { bd = d3; bj = j3; bw = 3; }
      od[ob + r] = bd;
      oj[ob + r] = bj;
      p0 += (bw == 0); p1 += (bw == 1); p2 += (bw == 2); p3 += (bw == 3);
    }
  }
  __syncthreads();

  // stage 2: 4 lists -> 1 (32 thr), write to ORIGINAL query row
  if (t < 32) {
    const int base = t * 65;
    int p0 = 0, p1 = 0, p2 = 0, p3 = 0;
    int* op = idx_out + (((size_t)b * NPTS + oq) << 4);   // thread t: ql==t -> own oq
    for (int r = 0; r < 16; ++r) {
      const float d0 = od[base + p0];
      const float d1 = od[base + 16 + p1];
      const float d2 = od[base + 32 + p2];
      const float d3 = od[base + 48 + p3];
      const unsigned short j0 = oj[base + p0];
      const unsigned short j1 = oj[base + 16 + p1];
      const unsigned short j2 = oj[base + 32 + p2];
      const unsigned short j3 = oj[base + 48 + p3];
      float bd = d0; unsigned short bj = j0; int bw = 0;
      if (d1 < bd || (d1 == bd && j1 < bj)) { bd = d1; bj = j1; bw = 1; }
      if (d2 < bd || (d2 == bd && j2 < bj)) { bd = d2; bj = j2; bw = 2; }
      if (d3 < bd || (d3 == bd && j3 < bj)) { bd = d3; bj = j3; bw = 3; }
      op[r] = (int)bj;
      p0 += (bw == 0); p1 += (bw == 1); p2 += (bw == 2); p3 += (bw == 3);
    }
  }
}

// ---------------- K2: fused MLP, ALL of W2 in LDS (R12, unchanged) ----------
__global__ __launch_bounds__(512) void mlp_kernel(const float* __restrict__ pts,
                                                  const int* __restrict__ idx,
                                                  const float* __restrict__ W1,
                                                  const float* __restrict__ b1,
                                                  const _Float16* __restrict__ W2F,
                                                  const float* __restrict__ b2,
                                                  float* __restrict__ out) {
  __shared__ _Float16 sB[73728];       // 144 KiB: all of W2, fragment-major

  const int bid = blockIdx.x;          // 512 = 4 batches * 128 blocks
  const int b   = bid >> 7;
  const int t   = threadIdx.x;
  const int wv  = t >> 6;              // 8 waves
  const int q0  = ((bid & 127) << 5) + (wv << 2);   // 4 queries per wave
  const float* P = pts + (size_t)b * NPTS * 3;
  const int l   = t & 63;
  const int r   = l & 15;
  const int kg  = l >> 4;

#pragma unroll
  for (int i = 0; i < 18; ++i) {
    const int j = i * 512 + t;
    *(f16x8*)(sB + (size_t)j * 8) = *(const f16x8*)(W2F + (size_t)j * 8);
  }

  float f[4][6];
#pragma unroll
  for (int qi = 0; qi < 4; ++qi) {
    const int qq = q0 + qi;
    const int nb = idx[(((size_t)b * NPTS + qq) << 4) + r];
    const float ax = P[qq * 3 + 0], ay = P[qq * 3 + 1], az = P[qq * 3 + 2];
    f[qi][0] = P[nb * 3 + 0] - ax;
    f[qi][1] = P[nb * 3 + 1] - ay;
    f[qi][2] = P[nb * 3 + 2] - az;
    f[qi][3] = ax; f[qi][4] = ay; f[qi][5] = az;
  }

  f16x8 af[4][6];
#pragma unroll
  for (int kt = 0; kt < 6; ++kt) {
    const int h0 = kt * 32 + kg * 8;
    const f32x4 bb0 = *(const f32x4*)(b1 + h0);
    const f32x4 bb1 = *(const f32x4*)(b1 + h0 + 4);
    f32x4 w0[6], w1[6];
#pragma unroll
    for (int in = 0; in < 6; ++in) {
      w0[in] = *(const f32x4*)(W1 + in * HDIM + h0);
      w1[in] = *(const f32x4*)(W1 + in * HDIM + h0 + 4);
    }
#pragma unroll
    for (int qi = 0; qi < 4; ++qi) {
      f32x4 a0 = bb0, a1 = bb1;
#pragma unroll
      for (int in = 0; in < 6; ++in) {
        a0 += f[qi][in] * w0[in];
        a1 += f[qi][in] * w1[in];
      }
      f16x8 v;
#pragma unroll
      for (int j = 0; j < 4; ++j) {
        v[j]     = (_Float16)(a0[j] * __builtin_amdgcn_rcpf(1.0f + __expf(-a0[j])));
        v[j + 4] = (_Float16)(a1[j] * __builtin_amdgcn_rcpf(1.0f + __expf(-a1[j])));
      }
      af[qi][kt] = v;
    }
  }
  __syncthreads();

  const size_t orow = (size_t)b * NPTS + q0;
  const _Float16* bp = sB + (size_t)l * 8;

  for (int ct = 0; ct < 24; ++ct) {
    const int c = ct * 16 + r;
    f16x8 bfr[6];
#pragma unroll
    for (int kt = 0; kt < 6; ++kt)
      bfr[kt] = *(const f16x8*)(bp + (size_t)(ct * 6 + kt) * 512);

    f32x4 acc[4];
#pragma unroll
    for (int qi = 0; qi < 4; ++qi) acc[qi] = f32x4{0.f, 0.f, 0.f, 0.f};
#pragma unroll
    for (int kt = 0; kt < 6; ++kt)
#pragma unroll
      for (int qi = 0; qi < 4; ++qi)
        acc[qi] = __builtin_amdgcn_mfma_f32_16x16x32_f16(af[qi][kt], bfr[kt], acc[qi], 0, 0, 0);

    const float bb = b2[c];
#pragma unroll
    for (int qi = 0; qi < 4; ++qi) {
      float m = fmaxf(fmaxf(acc[qi][0], acc[qi][1]), fmaxf(acc[qi][2], acc[qi][3]));
      m = fmaxf(m, __shfl_xor(m, 16));
      m = fmaxf(m, __shfl_xor(m, 32));
      if (l < 16)
        out[(orow + qi) * CDIM + c] = m + bb;
    }
  }
}

extern "C" void kernel_launch(void* const* d_in, const int* in_sizes, int n_in,
                              void* d_out, int out_size, void* d_ws, size_t ws_size,
                              hipStream_t stream) {
  const float* point = (const float*)d_in[0];
  const float* W1    = (const float*)d_in[1];
  const float* b1    = (const float*)d_in[2];
  const float* W2    = (const float*)d_in[3];
  const float* b2    = (const float*)d_in[4];

  int*      idx_ws = (int*)d_ws;                                        // 1 MB
  float4*   sp4    = (float4*)((char*)d_ws + (1 << 20));                // 256 KB
  _Float16* W2F    = (_Float16*)((char*)d_ws + (1 << 20) + (256 << 10));// 144 KB
  float*    bnds   = (float*)((char*)d_ws + (1 << 20) + (512 << 10));   // 1 KB

  prep_w2<<<36, 256, 0, stream>>>(W2, W2F);
  bucket_kernel<<<NBATCH, 1024, 0, stream>>>(point, sp4, bnds);
  knn_kernel<<<512, 512, 0, stream>>>(sp4, bnds, idx_ws);
  mlp_kernel<<<512, 512, 0, stream>>>(point, idx_ws, W1, b1, W2F, b2, (float*)d_out);
}

// Round 17
// 240.264 us; speedup vs baseline: 1.2570x; 1.2570x over previous
//
#include <hip/hip_runtime.h>

#define NPTS 4096
#define NBATCH 4
#define HDIM 192
#define CDIM 384

typedef _Float16 f16x8 __attribute__((ext_vector_type(8)));
typedef float f32x4 __attribute__((ext_vector_type(4)));

// ---------------- K0: W2 [192][384] f32 -> fragment-major f16 chunks (R12, unchanged) --
__global__ __launch_bounds__(256) void prep_w2(const float* __restrict__ W2,
                                               _Float16* __restrict__ W2F) {
  const int j = blockIdx.x * 256 + threadIdx.x;   // 9216 chunks
  if (j < 9216) {
    const int lane = j & 63, r = lane & 15, kg = lane >> 4;
    const int kt = (j >> 6) % 6, ct = j / 384;
    const int c = ct * 16 + r, h0 = kt * 32 + kg * 8;
    f16x8 v;
#pragma unroll
    for (int e = 0; e < 8; ++e) v[e] = (_Float16)W2[(size_t)(h0 + e) * CDIM + c];
    *(f16x8*)(W2F + (size_t)j * 8) = v;
  }
}

// ---------------- K1: KNN — R12 VERBATIM (91us, brute-force + shared threshold) --------
// R13-R16 post-mortem: four spatial-pruning schedules (sorted slabs x3, buckets x2) all
// regressed vs this brute force (155/174/202/240 vs 91). For N=4096 uniform points the
// convergence stalls + imbalance + barriers cost more than the 67M distances. Keep.
#define SCAP 30
#define FINF 3.4e38f

// macro, not lambda: a [&] lambda address-takes dl/il -> scratch spill (R2 lesson)
#define PRUNE()                                                                      \
  do {                                                                               \
    int mc = cnt;                                                                    \
    _Pragma("unroll")                                                                \
    for (int s = 32; s; s >>= 1) { int o = __shfl_xor(mc, s); mc = mc > o ? mc : o; }\
    mc = __builtin_amdgcn_readfirstlane(mc);                                         \
    for (int e = 0; e < mc; ++e) {                                                   \
      const int j = sstk[sbase + e] & 4095;                                          \
      const float dx = qx - spx[j];                                                  \
      const float dy = qy - spy[j];                                                  \
      const float dz = qz - spz[j];                                                  \
      const float d = __fadd_rn(__fadd_rn(__fmul_rn(dx, dx), __fmul_rn(dy, dy)),     \
                                __fmul_rn(dz, dz));                                  \
      const float v = (e < cnt && d < dl[15]) ? d : FINF;                            \
      bool cc[16];                                                                   \
      _Pragma("unroll")                                                              \
      for (int i = 0; i < 16; ++i) cc[i] = v < dl[i];                                \
      _Pragma("unroll")                                                              \
      for (int i = 15; i >= 1; --i) {                                                \
        dl[i] = cc[i] ? (cc[i - 1] ? dl[i - 1] : v) : dl[i];                         \
        il[i] = cc[i] ? (cc[i - 1] ? il[i - 1] : j) : il[i];                         \
      }                                                                              \
      dl[0] = cc[0] ? v : dl[0];                                                     \
      il[0] = cc[0] ? j : il[0];                                                     \
    }                                                                                \
    cnt = 0;                                                                         \
    thr = dl[15];                                                                    \
    atomicMin(&sThrU[ql], __float_as_uint(dl[15]));                                  \
  } while (0)

__global__ __launch_bounds__(512) void knn_kernel(const float* __restrict__ pts,
                                                  int* __restrict__ idx_out) {
  __shared__ float smem[12352];
  __shared__ float sstk_f[7680];
  __shared__ unsigned sThrU[32];
  unsigned short* sstk = (unsigned short*)sstk_f;

  float* spx = smem;
  float* spy = smem + 4096;
  float* spz = smem + 8192;

  const int t  = threadIdx.x;
  const int b  = blockIdx.x >> 7;
  const int qb = (blockIdx.x & 127) << 5;
  const float* P = pts + (size_t)b * NPTS * 3;

  for (int i = t; i < NPTS; i += 512) {
    spx[i] = P[3 * i + 0];
    spy[i] = P[3 * i + 1];
    spz[i] = P[3 * i + 2];
  }
  if (t < 32) sThrU[t] = __float_as_uint(FINF);
  __syncthreads();

  const int ql    = t & 31;
  const int q     = qb + ql;
  const int cid   = (t >> 5) & 15;
  const int cbase = cid << 8;
  const float qx = spx[q], qy = spy[q], qz = spz[q];

  float dl[16];
  int   il[16];
#pragma unroll
  for (int i = 0; i < 16; ++i) { dl[i] = FINF; il[i] = 0; }
  float thr = FINF;
  int   cnt = 0;
  const int sbase = t * SCAP;

  for (int jt = 0; jt < 256; jt += 8) {
    {  // refresh admission threshold (volatile: must observe other waves' atomicMin)
      const unsigned tb = ((volatile unsigned*)sThrU)[ql];
      thr = fminf(dl[15], __uint_as_float(tb));
    }
    const int jb = cbase + jt;
    const f32x4 x0 = *(const f32x4*)(spx + jb);
    const f32x4 x1 = *(const f32x4*)(spx + jb + 4);
    const f32x4 y0 = *(const f32x4*)(spy + jb);
    const f32x4 y1 = *(const f32x4*)(spy + jb + 4);
    const f32x4 z0 = *(const f32x4*)(spz + jb);
    const f32x4 z1 = *(const f32x4*)(spz + jb + 4);
#pragma unroll
    for (int u = 0; u < 8; ++u) {
      const float px = (u < 4) ? x0[u & 3] : x1[u & 3];
      const float py = (u < 4) ? y0[u & 3] : y1[u & 3];
      const float pz = (u < 4) ? z0[u & 3] : z1[u & 3];
      const float dx = qx - px;
      const float dy = qy - py;
      const float dz = qz - pz;
      // EXACT match to numpy/jax: ((dx*dx + dy*dy) + dz*dz), f32, no FMA contraction
      const float d = __fadd_rn(__fadd_rn(__fmul_rn(dx, dx), __fmul_rn(dy, dy)),
                                __fmul_rn(dz, dz));
      if (d <= thr) { sstk[sbase + cnt] = (unsigned short)(jb + u); ++cnt; }
    }
    if (__any(cnt >= SCAP - 8)) PRUNE();
  }
  PRUNE();

  __syncthreads();

  float*          md = smem;
  unsigned short* mi = (unsigned short*)(smem + 8224);
  const int lbase = ql * 257 + cid * 16;
#pragma unroll
  for (int i = 0; i < 16; ++i) {
    md[lbase + i] = dl[i];
    mi[lbase + i] = (unsigned short)il[i];
  }
  __syncthreads();

  float*          od = sstk_f;
  unsigned short* oi = (unsigned short*)(sstk_f + 2080);
  if (t < 128) {
    const int mq = t >> 2, g = t & 3;
    const int base = mq * 257 + g * 64;
    int p0 = 0, p1 = 0, p2 = 0, p3 = 0;
    const int ob = mq * 65 + g * 16;
    for (int r = 0; r < 16; ++r) {
      const float d0 = md[base + p0];
      const float d1 = md[base + 16 + p1];
      const float d2 = md[base + 32 + p2];
      const float d3 = md[base + 48 + p3];
      int bw = 0; float bd = d0;
      if (d1 < bd) { bd = d1; bw = 1; }
      if (d2 < bd) { bd = d2; bw = 2; }
      if (d3 < bd) { bd = d3; bw = 3; }
      const unsigned short bi = (bw == 0) ? mi[base + p0]
                              : (bw == 1) ? mi[base + 16 + p1]
                              : (bw == 2) ? mi[base + 32 + p2]
                                          : mi[base + 48 + p3];
      od[ob + r] = bd;
      oi[ob + r] = bi;
      p0 += (bw == 0); p1 += (bw == 1); p2 += (bw == 2); p3 += (bw == 3);
    }
  }
  __syncthreads();

  if (t < 32) {
    const int base = t * 65;
    int p0 = 0, p1 = 0, p2 = 0, p3 = 0;
    int* op = idx_out + (((size_t)b * NPTS + qb + t) << 4);
    for (int r = 0; r < 16; ++r) {
      const float d0 = od[base + p0];
      const float d1 = od[base + 16 + p1];
      const float d2 = od[base + 32 + p2];
      const float d3 = od[base + 48 + p3];
      int bw = 0; float bd = d0;
      if (d1 < bd) { bd = d1; bw = 1; }
      if (d2 < bd) { bd = d2; bw = 2; }
      if (d3 < bd) { bd = d3; bw = 3; }
      const unsigned short bi = (bw == 0) ? oi[base + p0]
                              : (bw == 1) ? oi[base + 16 + p1]
                              : (bw == 2) ? oi[base + 32 + p2]
                                          : oi[base + 48 + p3];
      op[r] = (int)bi;
      p0 += (bw == 0); p1 += (bw == 1); p2 += (bw == 2); p3 += (bw == 3);
    }
  }
}

// ---------------- K2: fused MLP — HALF of W2 in LDS (72 KB), 2 blocks/CU -------------
// R12's mlp (144KB LDS, 1 block/CU, 2 waves/SIMD) was ~53us vs ~6us issue-bound: the
// serial fill->barrier->compute chain had nothing co-resident to hide it. Split: block
// stages 12 of 24 ct-tiles (half of W2F) and computes those 192 channels; grid x2
// (1024 blocks) -> 2 blocks/CU, 4 waves/SIMD, fill/compute of neighbor blocks overlap.
// Staging math + fragment layout byte-identical to R12 (numerics unchanged).
__global__ __launch_bounds__(512) void mlp_kernel(const float* __restrict__ pts,
                                                  const int* __restrict__ idx,
                                                  const float* __restrict__ W1,
                                                  const float* __restrict__ b1,
                                                  const _Float16* __restrict__ W2F,
                                                  const float* __restrict__ b2,
                                                  float* __restrict__ out) {
  __shared__ _Float16 sB[36864];       // 72 KiB: HALF of W2, fragment-major

  const int bid = blockIdx.x;          // 1024 = 4 batches * 128 query-groups * 2 halves
  const int b   = bid >> 8;
  const int g   = bid & 255;
  const int qg  = g >> 1;              // query group 0..127
  const int h   = g & 1;               // W2 half 0/1 (ct-tiles 12h .. 12h+11)
  const int t   = threadIdx.x;
  const int wv  = t >> 6;              // 8 waves
  const int q0  = (qg << 5) + (wv << 2);   // 4 queries per wave
  const float* P = pts + (size_t)b * NPTS * 3;
  const int l   = t & 63;
  const int r   = l & 15;
  const int kg  = l >> 4;

  // ---- fill LDS with this half's 4608 chunks (lane-linear, conflict-free) ----
#pragma unroll
  for (int i = 0; i < 9; ++i) {
    const int jl = i * 512 + t;                  // local chunk 0..4607
    *(f16x8*)(sB + (size_t)jl * 8) = *(const f16x8*)(W2F + (size_t)(h * 4608 + jl) * 8);
  }

  // ---- gathers: 4 queries, neighbor slot r each ----
  float f[4][6];
#pragma unroll
  for (int qi = 0; qi < 4; ++qi) {
    const int qq = q0 + qi;
    const int nb = idx[(((size_t)b * NPTS + qq) << 4) + r];
    const float ax = P[qq * 3 + 0], ay = P[qq * 3 + 1], az = P[qq * 3 + 2];
    f[qi][0] = P[nb * 3 + 0] - ax;
    f[qi][1] = P[nb * 3 + 1] - ay;
    f[qi][2] = P[nb * 3 + 2] - az;
    f[qi][3] = ax; f[qi][4] = ay; f[qi][5] = az;
  }

  // ---- stage layer1 -> A-fragments in registers (identical numerics to R12) ----
  f16x8 af[4][6];
#pragma unroll
  for (int kt = 0; kt < 6; ++kt) {
    const int h0 = kt * 32 + kg * 8;
    const f32x4 bb0 = *(const f32x4*)(b1 + h0);
    const f32x4 bb1 = *(const f32x4*)(b1 + h0 + 4);
    f32x4 w0[6], w1[6];
#pragma unroll
    for (int in = 0; in < 6; ++in) {
      w0[in] = *(const f32x4*)(W1 + in * HDIM + h0);
      w1[in] = *(const f32x4*)(W1 + in * HDIM + h0 + 4);
    }
#pragma unroll
    for (int qi = 0; qi < 4; ++qi) {
      f32x4 a0 = bb0, a1 = bb1;
#pragma unroll
      for (int in = 0; in < 6; ++in) {
        a0 += f[qi][in] * w0[in];
        a1 += f[qi][in] * w1[in];
      }
      f16x8 v;
#pragma unroll
      for (int j = 0; j < 4; ++j) {   // same swish expression as R4..R12 (absmax-stable)
        v[j]     = (_Float16)(a0[j] * __builtin_amdgcn_rcpf(1.0f + __expf(-a0[j])));
        v[j + 4] = (_Float16)(a1[j] * __builtin_amdgcn_rcpf(1.0f + __expf(-a1[j])));
      }
      af[qi][kt] = v;
    }
  }
  __syncthreads();   // LDS fill complete (fill loads + staging overlap above)

  // ---- MFMA + maxpool over this half's 12 channel tiles; B from LDS ----
  const size_t orow = (size_t)b * NPTS + q0;
  const _Float16* bp = sB + (size_t)l * 8;   // chunk position == lane

  for (int ct = 0; ct < 12; ++ct) {
    const int c = (h * 12 + ct) * 16 + r;    // global output channel
    f16x8 bfr[6];
#pragma unroll
    for (int kt = 0; kt < 6; ++kt)
      bfr[kt] = *(const f16x8*)(bp + (size_t)(ct * 6 + kt) * 512);  // local chunk offset

    f32x4 acc[4];
#pragma unroll
    for (int qi = 0; qi < 4; ++qi) acc[qi] = f32x4{0.f, 0.f, 0.f, 0.f};
#pragma unroll
    for (int kt = 0; kt < 6; ++kt)
#pragma unroll
      for (int qi = 0; qi < 4; ++qi)
        acc[qi] = __builtin_amdgcn_mfma_f32_16x16x32_f16(af[qi][kt], bfr[kt], acc[qi], 0, 0, 0);

    const float bb = b2[c];
    // C/D: col=lane&15 (=channel), row=(lane>>4)*4+reg (=neighbor) -> max over rows
#pragma unroll
    for (int qi = 0; qi < 4; ++qi) {
      float m = fmaxf(fmaxf(acc[qi][0], acc[qi][1]), fmaxf(acc[qi][2], acc[qi][3]));
      m = fmaxf(m, __shfl_xor(m, 16));
      m = fmaxf(m, __shfl_xor(m, 32));
      if (l < 16)
        out[(orow + qi) * CDIM + c] = m + bb;
    }
  }
}

extern "C" void kernel_launch(void* const* d_in, const int* in_sizes, int n_in,
                              void* d_out, int out_size, void* d_ws, size_t ws_size,
                              hipStream_t stream) {
  const float* point = (const float*)d_in[0];
  const float* W1    = (const float*)d_in[1];
  const float* b1    = (const float*)d_in[2];
  const float* W2    = (const float*)d_in[3];
  const float* b2    = (const float*)d_in[4];

  int*      idx_ws = (int*)d_ws;                                  // 1 MB
  _Float16* W2F    = (_Float16*)((char*)d_ws + (1 << 20));        // 144 KB

  prep_w2<<<36, 256, 0, stream>>>(W2, W2F);
  knn_kernel<<<512, 512, 0, stream>>>(point, idx_ws);
  mlp_kernel<<<1024, 512, 0, stream>>>(point, idx_ws, W1, b1, W2F, b2, (float*)d_out);
}